// Round 1
// baseline (74.208 us; speedup 1.0000x reference)
//
#include <hip/hip_runtime.h>
#include <math.h>

#define NB 32
#define NT 128
#define KD 16
#define HK 64      // H*K = 4*16
#define XD 80      // HK + KD
#define NH1 256
#define NH2 256
#define NA 2

// ws layout (floats)
#define WQT_OFF 0
#define WKT_OFF 1024
#define WVT_OFF 2048
#define W1T_OFF 3072
#define W2T_OFF (3072 + XD*NH1)           // 3072 + 20480 = 23552
#define WS_FLOATS (W2T_OFF + NH1*NH2)     // 89088 floats = 356 KB

__global__ __launch_bounds__(256) void transpose_weights(
    const float* __restrict__ Wq, const float* __restrict__ Wk, const float* __restrict__ Wv,
    const float* __restrict__ W1, const float* __restrict__ W2, float* __restrict__ ws)
{
    int tid = blockIdx.x * blockDim.x + threadIdx.x;
    int nth = gridDim.x * blockDim.x;
    // WqT/WkT/WvT: [k][o], k<16, o<64
    for (int idx = tid; idx < HK * KD; idx += nth) {
        int k = idx >> 6, o = idx & 63;
        ws[WQT_OFF + idx] = Wq[o * KD + k];
        ws[WKT_OFF + idx] = Wk[o * KD + k];
        ws[WVT_OFF + idx] = Wv[o * KD + k];
    }
    // W1T: [kk][o], kk<80, o<256
    for (int idx = tid; idx < XD * NH1; idx += nth) {
        int kk = idx >> 8, o = idx & 255;
        ws[W1T_OFF + idx] = W1[o * XD + kk];
    }
    // W2T: [kk][o], kk<256, o<256
    for (int idx = tid; idx < NH1 * NH2; idx += nth) {
        int kk = idx >> 8, o = idx & 255;
        ws[W2T_OFF + idx] = W2[o * NH1 + kk];
    }
}

__global__ __launch_bounds__(256) void actor_kernel(
    const float* __restrict__ state, const float* __restrict__ eps,
    const float* __restrict__ bq, const float* __restrict__ bk, const float* __restrict__ bv,
    const float* __restrict__ b1, const float* __restrict__ b2,
    const float* __restrict__ Wmu, const float* __restrict__ bmu,
    const float* __restrict__ Wls, const float* __restrict__ bls,
    const float* __restrict__ ws,
    float* __restrict__ out)
{
    __shared__ float s_state[NT][KD];   // 8 KB, batch b's full agent set
    __shared__ float s_x[4][XD];        // attention out + state concat, per row
    __shared__ float s_h1[4][NH1];
    __shared__ float s_h2[4][NH2];
    __shared__ float s_head[4][4];      // mu0, mu1, ls0, ls1 per row

    const int tid  = threadIdx.x;
    const int wave = tid >> 6;
    const int lane = tid & 63;
    const int b     = blockIdx.x >> 5;  // 32 i-tiles of 4 per batch
    const int itile = blockIdx.x & 31;
    const int i     = itile * 4 + wave;

    // ---- stage state[b,:,:] (2048 floats) into LDS, coalesced float4 ----
    {
        const float4* g4 = (const float4*)(state + (size_t)b * NT * KD);
        float4* s4 = (float4*)(&s_state[0][0]);
        #pragma unroll
        for (int idx = tid; idx < NT * KD / 4; idx += 256) s4[idx] = g4[idx];
    }
    __syncthreads();

    // ---- attention: wave handles row i, lane o = h*16+k output element ----
    const int o = lane;
    const float* WqT = ws + WQT_OFF;
    const float* WkT = ws + WKT_OFF;
    const float* WvT = ws + WVT_OFF;

    float wk[KD], wv[KD], si[KD];
    #pragma unroll
    for (int k = 0; k < KD; ++k) {
        wk[k] = WkT[k * HK + o];        // lane-consecutive: coalesced
        wv[k] = WvT[k * HK + o];
        si[k] = s_state[i][k];          // broadcast
    }
    // q_o = relu(dot(s_i, Wq[o]) + bq[o])
    float qo = bq[o];
    #pragma unroll
    for (int k = 0; k < KD; ++k) qo = fmaf(si[k], WqT[k * HK + o], qo);
    qo = fmaxf(qo, 0.f);
    // fold -dot(s_i, W) into bias: dot(rel_j,W) = dot(s_j,W) - dot(s_i,W)
    float cK = 0.f, cV = 0.f;
    #pragma unroll
    for (int k = 0; k < KD; ++k) { cK = fmaf(si[k], wk[k], cK); cV = fmaf(si[k], wv[k], cV); }
    const float bko = bk[o] - cK;
    const float bvo = bv[o] - cV;

    float m = -1e30f, l = 0.f, acc = 0.f;
    for (int j = 0; j < NT; ++j) {
        const float4* sj = (const float4*)(&s_state[j][0]);  // broadcast b128 reads
        float kt = bko, vt = bvo;
        #pragma unroll
        for (int q4 = 0; q4 < 4; ++q4) {
            float4 sv = sj[q4];
            kt = fmaf(sv.x, wk[q4*4+0], kt); vt = fmaf(sv.x, wv[q4*4+0], vt);
            kt = fmaf(sv.y, wk[q4*4+1], kt); vt = fmaf(sv.y, wv[q4*4+1], vt);
            kt = fmaf(sv.z, wk[q4*4+2], kt); vt = fmaf(sv.z, wv[q4*4+2], vt);
            kt = fmaf(sv.w, wk[q4*4+3], kt); vt = fmaf(sv.w, wv[q4*4+3], vt);
        }
        kt = fmaxf(kt, 0.f);
        vt = fmaxf(vt, 0.f);
        // s[h] = sum over the 16 lanes of this head group, then /sqrt(16)
        float sp = kt * qo;
        sp += __shfl_xor(sp, 1);
        sp += __shfl_xor(sp, 2);
        sp += __shfl_xor(sp, 4);
        sp += __shfl_xor(sp, 8);
        sp *= 0.25f;
        // online softmax (m,l redundant across the 16 lanes of a head)
        float mn = fmaxf(m, sp);
        float sc = __expf(m - mn);
        float p  = __expf(sp - mn);
        l   = l * sc + p;
        acc = acc * sc + p * vt;
        m = mn;
    }
    s_x[wave][o] = acc / l;
    if (o < KD) s_x[wave][HK + o] = s_state[i][o];
    __syncthreads();

    // ---- layer 1: h1[r][t] = relu(b1 + x[r] . W1[t,:]), W1T coalesced ----
    {
        const float* W1T = ws + W1T_OFF;
        float a0 = b1[tid], a1 = a0, a2 = a0, a3 = a0;
        for (int kk = 0; kk < XD; ++kk) {
            float w = W1T[kk * NH1 + tid];
            a0 = fmaf(s_x[0][kk], w, a0);
            a1 = fmaf(s_x[1][kk], w, a1);
            a2 = fmaf(s_x[2][kk], w, a2);
            a3 = fmaf(s_x[3][kk], w, a3);
        }
        s_h1[0][tid] = fmaxf(a0, 0.f);
        s_h1[1][tid] = fmaxf(a1, 0.f);
        s_h1[2][tid] = fmaxf(a2, 0.f);
        s_h1[3][tid] = fmaxf(a3, 0.f);
    }
    __syncthreads();

    // ---- layer 2 ----
    {
        const float* W2T = ws + W2T_OFF;
        float a0 = b2[tid], a1 = a0, a2 = a0, a3 = a0;
        for (int kk = 0; kk < NH1; ++kk) {
            float w = W2T[kk * NH2 + tid];
            a0 = fmaf(s_h1[0][kk], w, a0);
            a1 = fmaf(s_h1[1][kk], w, a1);
            a2 = fmaf(s_h1[2][kk], w, a2);
            a3 = fmaf(s_h1[3][kk], w, a3);
        }
        s_h2[0][tid] = fmaxf(a0, 0.f);
        s_h2[1][tid] = fmaxf(a1, 0.f);
        s_h2[2][tid] = fmaxf(a2, 0.f);
        s_h2[3][tid] = fmaxf(a3, 0.f);
    }
    __syncthreads();

    // ---- heads: 16 dots of 256 (4 rows x {mu0,mu1,ls0,ls1}) ----
    {
        int r = tid >> 6, g = (tid >> 4) & 3, ln = tid & 15;
        const float* Wrow = (g == 0) ? Wmu : (g == 1) ? (Wmu + NH2)
                          : (g == 2) ? Wls : (Wls + NH2);
        float part = 0.f;
        for (int kk = ln; kk < NH2; kk += 16) part = fmaf(s_h2[r][kk], Wrow[kk], part);
        part += __shfl_xor(part, 1);
        part += __shfl_xor(part, 2);
        part += __shfl_xor(part, 4);
        part += __shfl_xor(part, 8);
        if (ln == 0) {
            float bias = (g == 0) ? bmu[0] : (g == 1) ? bmu[1] : (g == 2) ? bls[0] : bls[1];
            s_head[r][g] = tanhf(part + bias);
        }
    }
    __syncthreads();

    // ---- finalize: rsample + tanh squash + log_prob, one thread per row ----
    if (tid < 4) {
        int r = tid;
        int row = b * NT + itile * 4 + r;
        float lp = 0.f;
        #pragma unroll
        for (int d = 0; d < NA; ++d) {
            float mu  = s_head[r][d];
            float lsr = s_head[r][2 + d];
            float ls  = -20.f + 11.f * (lsr + 1.f);   // LOG_STD_MIN + 0.5*range*(x+1)
            float sd  = __expf(ls);
            float e   = eps[row * NA + d];
            float z   = mu + sd * e;
            float a   = tanhf(z);
            out[row * NA + d] = a;
            lp += -0.5f * e * e - ls - 0.91893853320467274f - __logf(1.f - a * a + 1e-7f);
        }
        out[NB * NT * NA + row] = lp;
    }
}

extern "C" void kernel_launch(void* const* d_in, const int* in_sizes, int n_in,
                              void* d_out, int out_size, void* d_ws, size_t ws_size,
                              hipStream_t stream) {
    const float* state = (const float*)d_in[0];
    const float* eps   = (const float*)d_in[1];
    const float* Wq    = (const float*)d_in[2];
    const float* bq    = (const float*)d_in[3];
    const float* Wk    = (const float*)d_in[4];
    const float* bk    = (const float*)d_in[5];
    const float* Wv    = (const float*)d_in[6];
    const float* bv    = (const float*)d_in[7];
    const float* W1    = (const float*)d_in[8];
    const float* b1    = (const float*)d_in[9];
    const float* W2    = (const float*)d_in[10];
    const float* b2    = (const float*)d_in[11];
    const float* Wmu   = (const float*)d_in[12];
    const float* bmu   = (const float*)d_in[13];
    const float* Wls   = (const float*)d_in[14];
    const float* bls   = (const float*)d_in[15];
    float* out = (float*)d_out;
    float* ws  = (float*)d_ws;   // needs 356 KB; harness workspace is larger

    transpose_weights<<<64, 256, 0, stream>>>(Wq, Wk, Wv, W1, W2, ws);
    actor_kernel<<<NB * (NT / 4), 256, 0, stream>>>(
        state, eps, bq, bk, bv, b1, b2, Wmu, bmu, Wls, bls, ws, out);
}

// Round 2
// 42.311 us; speedup vs baseline: 1.7538x; 1.7538x over previous
//
#include <hip/hip_runtime.h>
#include <math.h>

#define NB 32
#define NT 128
#define KD 16
#define HK 64      // H*K
#define XD 80      // HK + KD
#define NH1 256
#define NH2 256
#define NA 2

// ws offsets in 32-bit words
#define WQT_OFF 0
#define WKT_OFF 1024
#define WVT_OFF 2048
#define W1Q_OFF 3072                 // uint2 [20][256]  (bf16-packed W1^T)
#define W2Q_OFF 13312                // uint2 [64][256]  (bf16-packed W2^T)
// total words: 13312 + 32768 = 46080 (180 KB)

// shared offsets in floats
#define S_STATE 0                    // [128][16]            2048
#define S_PK    2048                 // [64][65] o-major     4160
#define S_PV    6208                 // [64][64] j-major     4096
#define S_Q     10304                // [8][64]               512
#define S_PKI   10816                // [8][64]               512
#define S_PVI   11328                // [8][64]               512
#define S_X     11840                // [8][80]               640
#define S_HEAD  12480                // [8][4]                 32
#define S_TOTAL 12512                // 50,048 B  (< 64 KB static)
#define S_H1    S_PK                 // MLP aliases Pk/Pv region after attention
#define S_H2    (S_PK + 2048)

__device__ __forceinline__ unsigned bf16rne(float f) {
    unsigned u = __float_as_uint(f);
    return (u + 0x7fffu + ((u >> 16) & 1u)) >> 16;
}

__global__ __launch_bounds__(256) void prep_weights(
    const float* __restrict__ Wq, const float* __restrict__ Wk, const float* __restrict__ Wv,
    const float* __restrict__ W1, const float* __restrict__ W2, unsigned* __restrict__ ws)
{
    int tid = blockIdx.x * blockDim.x + threadIdx.x;
    int nth = gridDim.x * blockDim.x;
    float* wsf = (float*)ws;
    // WqT/WkT/WvT: [k][o]
    for (int idx = tid; idx < HK * KD; idx += nth) {
        int k = idx >> 6, o = idx & 63;
        wsf[WQT_OFF + idx] = Wq[o * KD + k];
        wsf[WKT_OFF + idx] = Wk[o * KD + k];
        wsf[WVT_OFF + idx] = Wv[o * KD + k];
    }
    // W1 bf16-pack: [kk4][n], uint2 = 4 consecutive kk
    for (int idx = tid; idx < (XD / 4) * NH1; idx += nth) {
        int kk4 = idx >> 8, n = idx & 255;
        const float* wrow = W1 + n * XD + kk4 * 4;
        unsigned lo = bf16rne(wrow[0]) | (bf16rne(wrow[1]) << 16);
        unsigned hi = bf16rne(wrow[2]) | (bf16rne(wrow[3]) << 16);
        ((uint2*)(ws + W1Q_OFF))[idx] = make_uint2(lo, hi);
    }
    // W2 bf16-pack: [kk4][n]
    for (int idx = tid; idx < (NH1 / 4) * NH2; idx += nth) {
        int kk4 = idx >> 8, n = idx & 255;
        const float* wrow = W2 + n * NH1 + kk4 * 4;
        unsigned lo = bf16rne(wrow[0]) | (bf16rne(wrow[1]) << 16);
        unsigned hi = bf16rne(wrow[2]) | (bf16rne(wrow[3]) << 16);
        ((uint2*)(ws + W2Q_OFF))[idx] = make_uint2(lo, hi);
    }
}

__device__ __forceinline__ void attn_chunk(
    float* sm, const float* q, const float* beff, float bveff,
    int h16, int s, int lane, float& mrun, float& lrun, float& acc)
{
    // scores: lane (h,s) owns j_local = s + 16*jj, jj=0..3
    float sc[4] = {0.f, 0.f, 0.f, 0.f};
    #pragma unroll
    for (int k = 0; k < KD; ++k) {
        const float* pkr = sm + S_PK + (h16 + k) * 65 + s;
        float bk_ = beff[k], qk = q[k];
        #pragma unroll
        for (int jj = 0; jj < 4; ++jj) {
            float t = fmaxf(pkr[16 * jj] + bk_, 0.f);
            sc[jj] = fmaf(t, qk, sc[jj]);
        }
    }
    #pragma unroll
    for (int jj = 0; jj < 4; ++jj) sc[jj] *= 0.25f;   // 1/sqrt(16)
    // head max over 16 lanes
    float cm = fmaxf(fmaxf(sc[0], sc[1]), fmaxf(sc[2], sc[3]));
    cm = fmaxf(cm, __shfl_xor(cm, 1));
    cm = fmaxf(cm, __shfl_xor(cm, 2));
    cm = fmaxf(cm, __shfl_xor(cm, 4));
    cm = fmaxf(cm, __shfl_xor(cm, 8));
    float mnew = fmaxf(mrun, cm);
    float scale = __expf(mrun - mnew);   // first chunk: exp(-1e30-..) -> 0
    float p[4];
    #pragma unroll
    for (int jj = 0; jj < 4; ++jj) p[jj] = __expf(sc[jj] - mnew);
    float lsum = (p[0] + p[1]) + (p[2] + p[3]);
    lsum += __shfl_xor(lsum, 1);
    lsum += __shfl_xor(lsum, 2);
    lsum += __shfl_xor(lsum, 4);
    lsum += __shfl_xor(lsum, 8);
    lrun = fmaf(lrun, scale, lsum);
    // PV: lane o accumulates sum_j p_j * relu(Pv[j][o] + bveff)
    float pa = 0.f, pb = 0.f;
    #pragma unroll
    for (int jj = 0; jj < 4; ++jj) {
        #pragma unroll
        for (int sp = 0; sp < 16; sp += 2) {
            float w0 = __shfl(p[jj], h16 + sp);
            float w1 = __shfl(p[jj], h16 + sp + 1);
            float v0 = fmaxf(sm[S_PV + (16 * jj + sp) * 64 + lane] + bveff, 0.f);
            float v1 = fmaxf(sm[S_PV + (16 * jj + sp + 1) * 64 + lane] + bveff, 0.f);
            pa = fmaf(w0, v0, pa);
            pb = fmaf(w1, v1, pb);
        }
    }
    acc = fmaf(acc, scale, pa + pb);
    mrun = mnew;
}

__global__ __launch_bounds__(512) void actor_kernel(
    const float* __restrict__ state, const float* __restrict__ eps,
    const float* __restrict__ bq, const float* __restrict__ bk, const float* __restrict__ bv,
    const float* __restrict__ b1, const float* __restrict__ b2,
    const float* __restrict__ Wmu, const float* __restrict__ bmu,
    const float* __restrict__ Wls, const float* __restrict__ bls,
    const unsigned* __restrict__ ws, float* __restrict__ out)
{
    __shared__ float sm[S_TOTAL];
    const float* wsf = (const float*)ws;
    const int tid = threadIdx.x;
    const int w = tid >> 6, lane = tid & 63;
    const int b = blockIdx.x >> 4, tile = blockIdx.x & 15;
    const int i = tile * 8 + w;          // this wave's agent row

    // stage state[b] : 2048 floats = 512 float4, one per thread
    ((float4*)(sm + S_STATE))[tid] = ((const float4*)(state + (size_t)b * NT * KD))[tid];

    // per-lane projection weight columns (o = lane), coalesced
    float wq[KD], wk[KD], wv[KD];
    #pragma unroll
    for (int m = 0; m < KD; ++m) {
        wq[m] = wsf[WQT_OFF + m * 64 + lane];
        wk[m] = wsf[WKT_OFF + m * 64 + lane];
        wv[m] = wsf[WVT_OFF + m * 64 + lane];
    }
    __syncthreads();

    // ---- setup: q_i, Pk_i, Pv_i for this wave's row ----
    {
        float sj[KD];
        {
            const float4* s4 = (const float4*)(sm + S_STATE + i * KD);
            float4 t0 = s4[0], t1 = s4[1], t2 = s4[2], t3 = s4[3];
            sj[0]=t0.x; sj[1]=t0.y; sj[2]=t0.z; sj[3]=t0.w;
            sj[4]=t1.x; sj[5]=t1.y; sj[6]=t1.z; sj[7]=t1.w;
            sj[8]=t2.x; sj[9]=t2.y; sj[10]=t2.z; sj[11]=t2.w;
            sj[12]=t3.x; sj[13]=t3.y; sj[14]=t3.z; sj[15]=t3.w;
        }
        float aq = bq[lane], ak = 0.f, av = 0.f;
        #pragma unroll
        for (int m = 0; m < KD; ++m) {
            aq = fmaf(sj[m], wq[m], aq);
            ak = fmaf(sj[m], wk[m], ak);
            av = fmaf(sj[m], wv[m], av);
        }
        sm[S_Q   + w * 64 + lane] = fmaxf(aq, 0.f);
        sm[S_PKI + w * 64 + lane] = ak;
        sm[S_PVI + w * 64 + lane] = av;
    }
    // ---- chunk-0 precompute: Pk[o][j], Pv[j][o] for j in [0,64) ----
    #pragma unroll
    for (int jj = 0; jj < 8; ++jj) {
        int jl = w + 8 * jj;
        float sj[KD];
        {
            const float4* s4 = (const float4*)(sm + S_STATE + jl * KD);
            float4 t0 = s4[0], t1 = s4[1], t2 = s4[2], t3 = s4[3];
            sj[0]=t0.x; sj[1]=t0.y; sj[2]=t0.z; sj[3]=t0.w;
            sj[4]=t1.x; sj[5]=t1.y; sj[6]=t1.z; sj[7]=t1.w;
            sj[8]=t2.x; sj[9]=t2.y; sj[10]=t2.z; sj[11]=t2.w;
            sj[12]=t3.x; sj[13]=t3.y; sj[14]=t3.z; sj[15]=t3.w;
        }
        float ak = 0.f, av = 0.f;
        #pragma unroll
        for (int m = 0; m < KD; ++m) {
            ak = fmaf(sj[m], wk[m], ak);
            av = fmaf(sj[m], wv[m], av);
        }
        sm[S_PK + lane * 65 + jl] = ak;
        sm[S_PV + jl * 64 + lane] = av;
    }
    __syncthreads();

    // ---- attention registers ----
    const int h16 = lane & 48, s = lane & 15;
    float q[KD], beff[KD];
    #pragma unroll
    for (int k = 0; k < KD; ++k) {
        q[k]    = sm[S_Q + w * 64 + h16 + k];
        beff[k] = bk[h16 + k] - sm[S_PKI + w * 64 + h16 + k];
    }
    float bveff = bv[lane] - sm[S_PVI + w * 64 + lane];
    float mrun = -1e30f, lrun = 0.f, acc = 0.f;

    attn_chunk(sm, q, beff, bveff, h16, s, lane, mrun, lrun, acc);
    __syncthreads();

    // ---- chunk-1 precompute: j in [64,128) ----
    #pragma unroll
    for (int jj = 0; jj < 8; ++jj) {
        int jl = w + 8 * jj;
        float sj[KD];
        {
            const float4* s4 = (const float4*)(sm + S_STATE + (64 + jl) * KD);
            float4 t0 = s4[0], t1 = s4[1], t2 = s4[2], t3 = s4[3];
            sj[0]=t0.x; sj[1]=t0.y; sj[2]=t0.z; sj[3]=t0.w;
            sj[4]=t1.x; sj[5]=t1.y; sj[6]=t1.z; sj[7]=t1.w;
            sj[8]=t2.x; sj[9]=t2.y; sj[10]=t2.z; sj[11]=t2.w;
            sj[12]=t3.x; sj[13]=t3.y; sj[14]=t3.z; sj[15]=t3.w;
        }
        float ak = 0.f, av = 0.f;
        #pragma unroll
        for (int m = 0; m < KD; ++m) {
            ak = fmaf(sj[m], wk[m], ak);
            av = fmaf(sj[m], wv[m], av);
        }
        sm[S_PK + lane * 65 + jl] = ak;
        sm[S_PV + jl * 64 + lane] = av;
    }
    __syncthreads();

    attn_chunk(sm, q, beff, bveff, h16, s, lane, mrun, lrun, acc);

    sm[S_X + w * 80 + lane] = acc / lrun;
    if (lane < KD) sm[S_X + w * 80 + 64 + lane] = sm[S_STATE + i * KD + lane];
    __syncthreads();   // also retires all Pk/Pv reads before MLP aliases the region

    // ---- layer 1: 512 threads = neuron n x row-group g ----
    {
        const int n = tid & 255, g = tid >> 8, r0 = g * 4;
        const uint2* w1q = (const uint2*)(ws + W1Q_OFF);
        float a0 = b1[n], a1 = a0, a2 = a0, a3 = a0;
        const float4* xA = (const float4*)(sm + S_X + (r0 + 0) * 80);
        const float4* xB = (const float4*)(sm + S_X + (r0 + 1) * 80);
        const float4* xC = (const float4*)(sm + S_X + (r0 + 2) * 80);
        const float4* xD = (const float4*)(sm + S_X + (r0 + 3) * 80);
        #pragma unroll 4
        for (int kk4 = 0; kk4 < XD / 4; ++kk4) {
            uint2 wu = w1q[kk4 * 256 + n];
            float w0  = __uint_as_float(wu.x << 16);
            float w1_ = __uint_as_float(wu.x & 0xffff0000u);
            float w2_ = __uint_as_float(wu.y << 16);
            float w3_ = __uint_as_float(wu.y & 0xffff0000u);
            float4 va = xA[kk4];
            a0 = fmaf(va.x, w0, a0); a0 = fmaf(va.y, w1_, a0); a0 = fmaf(va.z, w2_, a0); a0 = fmaf(va.w, w3_, a0);
            float4 vb = xB[kk4];
            a1 = fmaf(vb.x, w0, a1); a1 = fmaf(vb.y, w1_, a1); a1 = fmaf(vb.z, w2_, a1); a1 = fmaf(vb.w, w3_, a1);
            float4 vc = xC[kk4];
            a2 = fmaf(vc.x, w0, a2); a2 = fmaf(vc.y, w1_, a2); a2 = fmaf(vc.z, w2_, a2); a2 = fmaf(vc.w, w3_, a2);
            float4 vd = xD[kk4];
            a3 = fmaf(vd.x, w0, a3); a3 = fmaf(vd.y, w1_, a3); a3 = fmaf(vd.z, w2_, a3); a3 = fmaf(vd.w, w3_, a3);
        }
        sm[S_H1 + (r0 + 0) * 256 + n] = fmaxf(a0, 0.f);
        sm[S_H1 + (r0 + 1) * 256 + n] = fmaxf(a1, 0.f);
        sm[S_H1 + (r0 + 2) * 256 + n] = fmaxf(a2, 0.f);
        sm[S_H1 + (r0 + 3) * 256 + n] = fmaxf(a3, 0.f);
    }
    __syncthreads();

    // ---- layer 2 ----
    {
        const int n = tid & 255, g = tid >> 8, r0 = g * 4;
        const uint2* w2q = (const uint2*)(ws + W2Q_OFF);
        float a0 = b2[n], a1 = a0, a2 = a0, a3 = a0;
        const float4* xA = (const float4*)(sm + S_H1 + (r0 + 0) * 256);
        const float4* xB = (const float4*)(sm + S_H1 + (r0 + 1) * 256);
        const float4* xC = (const float4*)(sm + S_H1 + (r0 + 2) * 256);
        const float4* xD = (const float4*)(sm + S_H1 + (r0 + 3) * 256);
        #pragma unroll 4
        for (int kk4 = 0; kk4 < NH1 / 4; ++kk4) {
            uint2 wu = w2q[kk4 * 256 + n];
            float w0  = __uint_as_float(wu.x << 16);
            float w1_ = __uint_as_float(wu.x & 0xffff0000u);
            float w2_ = __uint_as_float(wu.y << 16);
            float w3_ = __uint_as_float(wu.y & 0xffff0000u);
            float4 va = xA[kk4];
            a0 = fmaf(va.x, w0, a0); a0 = fmaf(va.y, w1_, a0); a0 = fmaf(va.z, w2_, a0); a0 = fmaf(va.w, w3_, a0);
            float4 vb = xB[kk4];
            a1 = fmaf(vb.x, w0, a1); a1 = fmaf(vb.y, w1_, a1); a1 = fmaf(vb.z, w2_, a1); a1 = fmaf(vb.w, w3_, a1);
            float4 vc = xC[kk4];
            a2 = fmaf(vc.x, w0, a2); a2 = fmaf(vc.y, w1_, a2); a2 = fmaf(vc.z, w2_, a2); a2 = fmaf(vc.w, w3_, a2);
            float4 vd = xD[kk4];
            a3 = fmaf(vd.x, w0, a3); a3 = fmaf(vd.y, w1_, a3); a3 = fmaf(vd.z, w2_, a3); a3 = fmaf(vd.w, w3_, a3);
        }
        sm[S_H2 + (r0 + 0) * 256 + n] = fmaxf(a0, 0.f);
        sm[S_H2 + (r0 + 1) * 256 + n] = fmaxf(a1, 0.f);
        sm[S_H2 + (r0 + 2) * 256 + n] = fmaxf(a2, 0.f);
        sm[S_H2 + (r0 + 3) * 256 + n] = fmaxf(a3, 0.f);
    }
    __syncthreads();

    // ---- heads: 32 groups of 16 lanes: (row r, output d) ----
    {
        const int g2 = tid >> 4, r = g2 >> 2, d = g2 & 3, ln = tid & 15;
        const float* wrow = (d < 2) ? (Wmu + d * NH2) : (Wls + (d - 2) * NH2);
        float part = 0.f;
        #pragma unroll
        for (int mm = 0; mm < 16; ++mm)
            part = fmaf(sm[S_H2 + r * 256 + ln + 16 * mm], wrow[ln + 16 * mm], part);
        part += __shfl_xor(part, 1);
        part += __shfl_xor(part, 2);
        part += __shfl_xor(part, 4);
        part += __shfl_xor(part, 8);
        if (ln == 0) {
            float bias = (d < 2) ? bmu[d] : bls[d - 2];
            sm[S_HEAD + r * 4 + d] = tanhf(part + bias);
        }
    }
    __syncthreads();

    // ---- finalize: rsample + squash + log_prob ----
    if (tid < 8) {
        const int r = tid;
        const int row = b * NT + tile * 8 + r;
        float lp = 0.f;
        #pragma unroll
        for (int d = 0; d < NA; ++d) {
            float mu  = sm[S_HEAD + r * 4 + d];
            float lsr = sm[S_HEAD + r * 4 + 2 + d];
            float ls  = -20.f + 11.f * (lsr + 1.f);
            float sd  = __expf(ls);
            float e   = eps[row * NA + d];
            float z   = mu + sd * e;
            float a   = tanhf(z);
            out[row * NA + d] = a;
            lp += -0.5f * e * e - ls - 0.91893853320467274f - __logf(1.f - a * a + 1e-7f);
        }
        out[NB * NT * NA + row] = lp;
    }
}

extern "C" void kernel_launch(void* const* d_in, const int* in_sizes, int n_in,
                              void* d_out, int out_size, void* d_ws, size_t ws_size,
                              hipStream_t stream) {
    const float* state = (const float*)d_in[0];
    const float* eps   = (const float*)d_in[1];
    const float* Wq    = (const float*)d_in[2];
    const float* bq    = (const float*)d_in[3];
    const float* Wk    = (const float*)d_in[4];
    const float* bk    = (const float*)d_in[5];
    const float* Wv    = (const float*)d_in[6];
    const float* bv    = (const float*)d_in[7];
    const float* W1    = (const float*)d_in[8];
    const float* b1    = (const float*)d_in[9];
    const float* W2    = (const float*)d_in[10];
    const float* b2    = (const float*)d_in[11];
    const float* Wmu   = (const float*)d_in[12];
    const float* bmu   = (const float*)d_in[13];
    const float* Wls   = (const float*)d_in[14];
    const float* bls   = (const float*)d_in[15];
    float* out   = (float*)d_out;
    unsigned* ws = (unsigned*)d_ws;

    prep_weights<<<64, 256, 0, stream>>>(Wq, Wk, Wv, W1, W2, ws);
    actor_kernel<<<NB * (NT / 8), 512, 0, stream>>>(
        state, eps, bq, bk, bv, b1, b2, Wmu, bmu, Wls, bls, ws, out);
}

// Round 3
// 29.807 us; speedup vs baseline: 2.4896x; 1.4195x over previous
//
#include <hip/hip_runtime.h>
#include <math.h>

#define NB 32
#define NT 128
#define KD 16
#define HK 64
#define XD 80
#define XP 96      // padded X row (bf16), cols 80..95 are zero
#define NH1 256
#define NH2 256

// ws byte offsets
#define QG_OFF   0u          // fp32 [4096][64]   1 MB
#define PKB_OFF  1048576u    // bf16 [32][128][64] 512 KB
#define PVT_OFF  1572864u    // bf16 [32][64][128] 512 KB (j-transposed)
#define XB_OFF   2097152u    // bf16 [4096][96]   768 KB
#define W1P_OFF  2883584u    // bf16 MFMA-frag packed, 48 KB
#define W2P_OFF  2932736u    // bf16 MFMA-frag packed, 128 KB

typedef short bf16x8 __attribute__((ext_vector_type(8)));
typedef float f32x4 __attribute__((ext_vector_type(4)));
union U4B8 { uint4 u; bf16x8 h; };

__device__ __forceinline__ unsigned short bf16rne(float f) {
    unsigned u = __float_as_uint(f);
    return (unsigned short)((u + 0x7fffu + ((u >> 16) & 1u)) >> 16);
}
__device__ __forceinline__ float bf2f(unsigned short h) {
    return __uint_as_float(((unsigned)h) << 16);
}
__device__ __forceinline__ void unpack8(uint4 u, float* f) {
    f[0] = __uint_as_float(u.x << 16); f[1] = __uint_as_float(u.x & 0xffff0000u);
    f[2] = __uint_as_float(u.y << 16); f[3] = __uint_as_float(u.y & 0xffff0000u);
    f[4] = __uint_as_float(u.z << 16); f[5] = __uint_as_float(u.z & 0xffff0000u);
    f[6] = __uint_as_float(u.w << 16); f[7] = __uint_as_float(u.w & 0xffff0000u);
}

// ---------------- K0: projections + weight packing ----------------
__global__ __launch_bounds__(256) void prep_kernel(
    const float* __restrict__ state,
    const float* __restrict__ Wq, const float* __restrict__ bq,
    const float* __restrict__ Wk, const float* __restrict__ Wv,
    const float* __restrict__ W1, const float* __restrict__ W2,
    char* __restrict__ wsb)
{
    const int blk = blockIdx.x, tid = threadIdx.x;
    float* Qg = (float*)(wsb + QG_OFF);
    unsigned short* PkB = (unsigned short*)(wsb + PKB_OFF);
    unsigned short* PvT = (unsigned short*)(wsb + PVT_OFF);
    unsigned short* W1P = (unsigned short*)(wsb + W1P_OFF);
    unsigned short* W2P = (unsigned short*)(wsb + W2P_OFF);

    if (blk < 128) {
        __shared__ float Wl[3][64][17];
        __shared__ float Sl[32][17];
        const int b = blk >> 2, r0 = (blk & 3) * 32;
        for (int idx = tid; idx < 1024; idx += 256) {
            int o = idx >> 4, m = idx & 15;
            Wl[0][o][m] = Wq[idx];
            Wl[1][o][m] = Wk[idx];
            Wl[2][o][m] = Wv[idx];
        }
        for (int idx = tid; idx < 512; idx += 256)
            Sl[idx >> 4][idx & 15] = state[(size_t)(b * NT + r0) * KD + idx];
        __syncthreads();
        const int o = tid & 63, rr = tid >> 6;
        float wqv[16], wkv[16], wvv[16];
        #pragma unroll
        for (int m = 0; m < 16; ++m) {
            wqv[m] = Wl[0][o][m]; wkv[m] = Wl[1][o][m]; wvv[m] = Wl[2][o][m];
        }
        const float bqo = bq[o];
        for (int r = rr; r < 32; r += 4) {
            float aq = bqo, ak = 0.f, av = 0.f;
            #pragma unroll
            for (int m = 0; m < 16; ++m) {
                float s = Sl[r][m];
                aq = fmaf(s, wqv[m], aq);
                ak = fmaf(s, wkv[m], ak);
                av = fmaf(s, wvv[m], av);
            }
            int row = b * NT + r0 + r;
            Qg[row * 64 + o]  = fmaxf(aq, 0.f);
            PkB[row * 64 + o] = bf16rne(ak);
            PvT[b * 8192 + o * NT + (r0 + r)] = bf16rne(av);
        }
    } else if (blk == 128) {
        // W1P: [ks(3)][w(4)][t(4)][lane(64)][j(8)] : 3072 uint4
        for (int it = 0; it < 12; ++it) {
            int fi = tid + it * 256;
            int l = fi & 63, rest = fi >> 6;
            int t = rest & 3, w = (rest >> 2) & 3, ks = rest >> 4;
            int n = w * 64 + t * 16 + (l & 15);
            int kb = ks * 32 + (l >> 4) * 8;
            unsigned short v[8];
            #pragma unroll
            for (int j = 0; j < 8; ++j) {
                int k = kb + j;
                v[j] = (k < XD) ? bf16rne(W1[n * XD + k]) : (unsigned short)0;
            }
            uint4 u;
            u.x = (unsigned)v[0] | ((unsigned)v[1] << 16);
            u.y = (unsigned)v[2] | ((unsigned)v[3] << 16);
            u.z = (unsigned)v[4] | ((unsigned)v[5] << 16);
            u.w = (unsigned)v[6] | ((unsigned)v[7] << 16);
            ((uint4*)W1P)[fi] = u;
        }
    } else {
        // W2P: [ks(8)][w(4)][t(4)][lane(64)][j(8)] : 8192 uint4 over 4 blocks
        int bb = blk - 129;
        for (int it = 0; it < 8; ++it) {
            int fi = bb * 2048 + tid + it * 256;
            int l = fi & 63, rest = fi >> 6;
            int t = rest & 3, w = (rest >> 2) & 3, ks = rest >> 4;
            int n = w * 64 + t * 16 + (l & 15);
            int kb = ks * 32 + (l >> 4) * 8;
            unsigned short v[8];
            #pragma unroll
            for (int j = 0; j < 8; ++j) v[j] = bf16rne(W2[n * NH1 + kb + j]);
            uint4 u;
            u.x = (unsigned)v[0] | ((unsigned)v[1] << 16);
            u.y = (unsigned)v[2] | ((unsigned)v[3] << 16);
            u.z = (unsigned)v[4] | ((unsigned)v[5] << 16);
            u.w = (unsigned)v[6] | ((unsigned)v[7] << 16);
            ((uint4*)W2P)[fi] = u;
        }
    }
}

// ---------------- K1: attention (one sync) ----------------
__global__ __launch_bounds__(256) void attn_kernel(
    const float* __restrict__ state,
    const float* __restrict__ bkg, const float* __restrict__ bvg,
    char* __restrict__ wsb)
{
    __shared__ __align__(16) unsigned short smPk[128 * 72];   // [j][64+pad], 144B stride
    __shared__ __align__(16) unsigned short smPv[64 * 136];   // [o][128+pad], 272B stride
    __shared__ __align__(16) float smP[16 * 68];              // [wave*4+h][64+pad]
    const int tid = threadIdx.x, w = tid >> 6, lane = tid & 63;
    const int b = blockIdx.x >> 5, tile = blockIdx.x & 31;
    const int i = tile * 4 + w;
    const float* Qg = (const float*)(wsb + QG_OFF);
    const unsigned short* PkB = (const unsigned short*)(wsb + PKB_OFF);
    const unsigned short* PvT = (const unsigned short*)(wsb + PVT_OFF);
    unsigned short* XB = (unsigned short*)(wsb + XB_OFF);

    // stage Pk (1024 uint4) and PvT (1024 uint4), bank-uniform writes
    {
        const uint4* src = (const uint4*)(PkB + (size_t)b * NT * 64);
        #pragma unroll
        for (int it = 0; it < 4; ++it) {
            int idx = tid + it * 256;
            int r = idx >> 3, c = idx & 7;
            *(uint4*)(smPk + r * 72 + c * 8) = src[idx];
        }
        const uint4* src2 = (const uint4*)(PvT + (size_t)b * 8192);
        #pragma unroll
        for (int it = 0; it < 4; ++it) {
            int idx = tid + it * 256;
            int o = idx >> 4, c = idx & 15;
            *(uint4*)(smPv + o * 136 + c * 8) = src2[idx];
        }
    }
    __syncthreads();

    const int h16 = lane & 48, s = lane & 15, h = lane >> 4;
    // q, beff (fold bk - Pk_i), bveff (fold bv - Pv_i)
    float q[16], beff[16];
    {
        const float4* qv  = (const float4*)(Qg + (size_t)(b * NT + i) * 64 + h16);
        const float4* bk4 = (const float4*)(bkg + h16);
        const uint4* pki = (const uint4*)(smPk + i * 72 + h16);
        float pf[16];
        unpack8(pki[0], pf); unpack8(pki[1], pf + 8);
        #pragma unroll
        for (int qq = 0; qq < 4; ++qq) {
            float4 qv4 = qv[qq], bv4 = bk4[qq];
            q[qq*4+0] = qv4.x; q[qq*4+1] = qv4.y; q[qq*4+2] = qv4.z; q[qq*4+3] = qv4.w;
            beff[qq*4+0] = bv4.x - pf[qq*4+0];
            beff[qq*4+1] = bv4.y - pf[qq*4+1];
            beff[qq*4+2] = bv4.z - pf[qq*4+2];
            beff[qq*4+3] = bv4.w - pf[qq*4+3];
        }
    }
    const float bveff = bvg[lane] - bf2f(smPv[lane * 136 + i]);

    // scores for all 128 j (lane of head h handles j = s + 16*jj)
    float sc[8];
    #pragma unroll
    for (int jj = 0; jj < 8; ++jj) {
        int j = s + 16 * jj;
        const uint4* pk = (const uint4*)(smPk + j * 72 + h16);
        float f[16];
        unpack8(pk[0], f); unpack8(pk[1], f + 8);
        float a = 0.f;
        #pragma unroll
        for (int k = 0; k < 16; ++k)
            a = fmaf(fmaxf(f[k] + beff[k], 0.f), q[k], a);
        sc[jj] = a * 0.25f;
    }
    // single-pass softmax across the 16-lane head group
    float m = sc[0];
    #pragma unroll
    for (int jj = 1; jj < 8; ++jj) m = fmaxf(m, sc[jj]);
    m = fmaxf(m, __shfl_xor(m, 1));
    m = fmaxf(m, __shfl_xor(m, 2));
    m = fmaxf(m, __shfl_xor(m, 4));
    m = fmaxf(m, __shfl_xor(m, 8));
    float l = 0.f;
    #pragma unroll
    for (int jj = 0; jj < 8; ++jj) { sc[jj] = __expf(sc[jj] - m); l += sc[jj]; }
    l += __shfl_xor(l, 1);
    l += __shfl_xor(l, 2);
    l += __shfl_xor(l, 4);
    l += __shfl_xor(l, 8);
    const float rl = 1.0f / l;
    float* pw = smP + (w * 4 + h) * 68;
    #pragma unroll
    for (int jj = 0; jj < 8; ++jj) pw[16 * jj + s] = sc[jj] * rl;
    __asm__ volatile("s_waitcnt lgkmcnt(0)" ::: "memory");

    // PV: lane o accumulates sum_j p[h(o)][j] * relu(Pv[o][j] + bveff)
    float acc = 0.f;
    #pragma unroll
    for (int u = 0; u < 16; ++u) {
        uint4 v = *(const uint4*)(smPv + lane * 136 + u * 8);
        float4 pa = *(const float4*)(pw + u * 8);
        float4 pb = *(const float4*)(pw + u * 8 + 4);
        float f[8];
        unpack8(v, f);
        acc = fmaf(pa.x, fmaxf(f[0] + bveff, 0.f), acc);
        acc = fmaf(pa.y, fmaxf(f[1] + bveff, 0.f), acc);
        acc = fmaf(pa.z, fmaxf(f[2] + bveff, 0.f), acc);
        acc = fmaf(pa.w, fmaxf(f[3] + bveff, 0.f), acc);
        acc = fmaf(pb.x, fmaxf(f[4] + bveff, 0.f), acc);
        acc = fmaf(pb.y, fmaxf(f[5] + bveff, 0.f), acc);
        acc = fmaf(pb.z, fmaxf(f[6] + bveff, 0.f), acc);
        acc = fmaf(pb.w, fmaxf(f[7] + bveff, 0.f), acc);
    }
    // write X row (bf16, K-padded to 96)
    const int row = b * NT + i;
    XB[(size_t)row * XP + lane] = bf16rne(acc);
    if (lane < 16)
        XB[(size_t)row * XP + 64 + lane] = bf16rne(state[(size_t)row * KD + lane]);
    else if (lane < 32)
        XB[(size_t)row * XP + 64 + lane] = 0;
}

// ---------------- K2: MLP + heads via MFMA ----------------
__global__ __launch_bounds__(256) void mlp_kernel(
    const float* __restrict__ eps,
    const float* __restrict__ b1g, const float* __restrict__ b2g,
    const float* __restrict__ Wmu, const float* __restrict__ bmu,
    const float* __restrict__ Wls, const float* __restrict__ bls,
    char* __restrict__ wsb, float* __restrict__ out)
{
    __shared__ __align__(16) unsigned short Xl[16 * 104];    // 208B stride
    __shared__ __align__(16) unsigned short H1l[16 * 264];   // 528B stride
    __shared__ __align__(16) unsigned short H2l[16 * 264];
    const int tid = threadIdx.x, wv = tid >> 6, l = tid & 63;
    const int r0 = blockIdx.x * 16;
    const unsigned short* XB = (const unsigned short*)(wsb + XB_OFF);
    const uint4* W1P = (const uint4*)(wsb + W1P_OFF);
    const uint4* W2P = (const uint4*)(wsb + W2P_OFF);

    if (tid < 192) {
        int row = tid / 12, c = tid % 12;
        *(uint4*)(Xl + row * 104 + c * 8) =
            *(const uint4*)(XB + (size_t)(r0 + row) * XP + c * 8);
    }
    __syncthreads();

    const int lr = l & 15, g = l >> 4;
    const f32x4 z4 = {0.f, 0.f, 0.f, 0.f};

    // layer 1: K=96 (3 k-steps), wave covers cols [64*wv, 64*wv+64)
    f32x4 acc[4];
    acc[0] = z4; acc[1] = z4; acc[2] = z4; acc[3] = z4;
    {
        uint4 a1[3];
        #pragma unroll
        for (int ks = 0; ks < 3; ++ks)
            a1[ks] = *(const uint4*)(Xl + lr * 104 + ks * 32 + g * 8);
        #pragma unroll
        for (int ks = 0; ks < 3; ++ks) {
            U4B8 av; av.u = a1[ks];
            #pragma unroll
            for (int t = 0; t < 4; ++t) {
                U4B8 bu; bu.u = W1P[((ks * 4 + wv) * 4 + t) * 64 + l];
                acc[t] = __builtin_amdgcn_mfma_f32_16x16x32_bf16(av.h, bu.h, acc[t], 0, 0, 0);
            }
        }
        #pragma unroll
        for (int t = 0; t < 4; ++t) {
            int n = wv * 64 + t * 16 + lr;
            float bn = b1g[n];
            #pragma unroll
            for (int qq = 0; qq < 4; ++qq)
                H1l[(4 * g + qq) * 264 + n] = bf16rne(fmaxf(acc[t][qq] + bn, 0.f));
        }
    }
    __syncthreads();

    // layer 2: K=256 (8 k-steps)
    acc[0] = z4; acc[1] = z4; acc[2] = z4; acc[3] = z4;
    {
        uint4 a2[8];
        #pragma unroll
        for (int ks = 0; ks < 8; ++ks)
            a2[ks] = *(const uint4*)(H1l + lr * 264 + ks * 32 + g * 8);
        #pragma unroll
        for (int ks = 0; ks < 8; ++ks) {
            U4B8 av; av.u = a2[ks];
            #pragma unroll
            for (int t = 0; t < 4; ++t) {
                U4B8 bu; bu.u = W2P[((ks * 4 + wv) * 4 + t) * 64 + l];
                acc[t] = __builtin_amdgcn_mfma_f32_16x16x32_bf16(av.h, bu.h, acc[t], 0, 0, 0);
            }
        }
        #pragma unroll
        for (int t = 0; t < 4; ++t) {
            int n = wv * 64 + t * 16 + lr;
            float bn = b2g[n];
            #pragma unroll
            for (int qq = 0; qq < 4; ++qq)
                H2l[(4 * g + qq) * 264 + n] = bf16rne(fmaxf(acc[t][qq] + bn, 0.f));
        }
    }
    __syncthreads();

    // heads + finalize: thread (m = tid>>4, cc = tid&15), k-slice cc*16..+15
    {
        const int m = tid >> 4, cc = tid & 15;
        float hbuf[16];
        uint4 ha = *(const uint4*)(H2l + m * 264 + cc * 16);
        uint4 hb = *(const uint4*)(H2l + m * 264 + cc * 16 + 8);
        unpack8(ha, hbuf); unpack8(hb, hbuf + 8);
        float d0 = 0.f, d1 = 0.f, d2 = 0.f, d3 = 0.f;
        #pragma unroll
        for (int kk = 0; kk < 16; ++kk) {
            int k = cc * 16 + kk;
            float hv = hbuf[kk];
            d0 = fmaf(hv, Wmu[k], d0);
            d1 = fmaf(hv, Wmu[256 + k], d1);
            d2 = fmaf(hv, Wls[k], d2);
            d3 = fmaf(hv, Wls[256 + k], d3);
        }
        #pragma unroll
        for (int off = 1; off < 16; off <<= 1) {
            d0 += __shfl_xor(d0, off);
            d1 += __shfl_xor(d1, off);
            d2 += __shfl_xor(d2, off);
            d3 += __shfl_xor(d3, off);
        }
        if (cc == 0) {
            int row = r0 + m;
            float mu0 = tanhf(d0 + bmu[0]);
            float mu1 = tanhf(d1 + bmu[1]);
            float t2  = tanhf(d2 + bls[0]);
            float t3  = tanhf(d3 + bls[1]);
            float ls0 = -20.f + 11.f * (t2 + 1.f);
            float ls1 = -20.f + 11.f * (t3 + 1.f);
            float e0 = eps[row * 2], e1 = eps[row * 2 + 1];
            float z0 = mu0 + __expf(ls0) * e0;
            float z1 = mu1 + __expf(ls1) * e1;
            float a0 = tanhf(z0), a1 = tanhf(z1);
            out[row * 2]     = a0;
            out[row * 2 + 1] = a1;
            float lp = -0.5f * e0 * e0 - ls0 - 0.91893853320467274f - __logf(1.f - a0 * a0 + 1e-7f)
                     + -0.5f * e1 * e1 - ls1 - 0.91893853320467274f - __logf(1.f - a1 * a1 + 1e-7f);
            out[NB * NT * 2 + row] = lp;
        }
    }
}

extern "C" void kernel_launch(void* const* d_in, const int* in_sizes, int n_in,
                              void* d_out, int out_size, void* d_ws, size_t ws_size,
                              hipStream_t stream) {
    const float* state = (const float*)d_in[0];
    const float* eps   = (const float*)d_in[1];
    const float* Wq    = (const float*)d_in[2];
    const float* bq    = (const float*)d_in[3];
    const float* Wk    = (const float*)d_in[4];
    const float* bk    = (const float*)d_in[5];
    const float* Wv    = (const float*)d_in[6];
    const float* bv    = (const float*)d_in[7];
    const float* W1    = (const float*)d_in[8];
    const float* b1    = (const float*)d_in[9];
    const float* W2    = (const float*)d_in[10];
    const float* b2    = (const float*)d_in[11];
    const float* Wmu   = (const float*)d_in[12];
    const float* bmu   = (const float*)d_in[13];
    const float* Wls   = (const float*)d_in[14];
    const float* bls   = (const float*)d_in[15];
    float* out = (float*)d_out;
    char* wsb  = (char*)d_ws;

    prep_kernel<<<133, 256, 0, stream>>>(state, Wq, bq, Wk, Wv, W1, W2, wsb);
    attn_kernel<<<NB * 32, 256, 0, stream>>>(state, bk, bv, wsb);
    mlp_kernel<<<256, 256, 0, stream>>>(eps, b1, b2, Wmu, bmu, Wls, bls, wsb, out);
}

// Round 4
// 23.147 us; speedup vs baseline: 3.2060x; 1.2878x over previous
//
#include <hip/hip_runtime.h>
#include <math.h>

#define NB 32
#define NT 128
#define KD 16
#define XD 80
#define NH1 256
#define NH2 256

// ws byte offsets
#define QG_OFF   0u          // f32 [4096][64]    1 MB
#define PKF_OFF  1048576u    // f32 [32][128][64] 2 MB
#define PVT_OFF  3145728u    // bf16 [32][64][128] 512 KB
#define W1P_OFF  3670016u    // bf16 MFMA frags, 48 KB
#define W2P_OFF  3719168u    // bf16 MFMA frags, 128 KB

typedef short bf16x8 __attribute__((ext_vector_type(8)));
typedef float f32x4 __attribute__((ext_vector_type(4)));
union U4B8 { uint4 u; bf16x8 h; };
union U4F16 { uint4 u; _Float16 h[8]; };

__device__ __forceinline__ unsigned short bf16rne(float f) {
    unsigned u = __float_as_uint(f);
    return (unsigned short)((u + 0x7fffu + ((u >> 16) & 1u)) >> 16);
}
__device__ __forceinline__ float bf2f(unsigned short h) {
    return __uint_as_float(((unsigned)h) << 16);
}
__device__ __forceinline__ void unpack8(uint4 u, float* f) {
    f[0] = __uint_as_float(u.x << 16); f[1] = __uint_as_float(u.x & 0xffff0000u);
    f[2] = __uint_as_float(u.y << 16); f[3] = __uint_as_float(u.y & 0xffff0000u);
    f[4] = __uint_as_float(u.z << 16); f[5] = __uint_as_float(u.z & 0xffff0000u);
    f[6] = __uint_as_float(u.w << 16); f[7] = __uint_as_float(u.w & 0xffff0000u);
}

// ---------------- K0: projections + MFMA weight packing ----------------
__global__ __launch_bounds__(256) void prep_kernel(
    const float* __restrict__ state,
    const float* __restrict__ Wq, const float* __restrict__ bq,
    const float* __restrict__ Wk, const float* __restrict__ Wv,
    const float* __restrict__ W1, const float* __restrict__ W2,
    char* __restrict__ wsb)
{
    const int blk = blockIdx.x, tid = threadIdx.x;
    float* Qg  = (float*)(wsb + QG_OFF);
    float* PkF = (float*)(wsb + PKF_OFF);
    unsigned short* PvT = (unsigned short*)(wsb + PVT_OFF);

    if (blk < 128) {
        __shared__ float Wl[3][64][17];
        __shared__ float Sl[32][17];
        const int b = blk >> 2, r0 = (blk & 3) * 32;
        for (int idx = tid; idx < 1024; idx += 256) {
            int o = idx >> 4, m = idx & 15;
            Wl[0][o][m] = Wq[idx];
            Wl[1][o][m] = Wk[idx];
            Wl[2][o][m] = Wv[idx];
        }
        for (int idx = tid; idx < 512; idx += 256)
            Sl[idx >> 4][idx & 15] = state[(size_t)(b * NT + r0) * KD + idx];
        __syncthreads();
        const int o = tid & 63, rr = tid >> 6;
        float wqv[16], wkv[16], wvv[16];
        #pragma unroll
        for (int m = 0; m < 16; ++m) {
            wqv[m] = Wl[0][o][m]; wkv[m] = Wl[1][o][m]; wvv[m] = Wl[2][o][m];
        }
        const float bqo = bq[o];
        for (int r = rr; r < 32; r += 4) {
            float aq = bqo, ak = 0.f, av = 0.f;
            #pragma unroll
            for (int m = 0; m < 16; ++m) {
                float s = Sl[r][m];
                aq = fmaf(s, wqv[m], aq);
                ak = fmaf(s, wkv[m], ak);
                av = fmaf(s, wvv[m], av);
            }
            int row = b * NT + r0 + r;
            Qg[row * 64 + o]  = fmaxf(aq, 0.f) * 0.25f;   // pre-scaled by 1/sqrt(16)
            PkF[row * 64 + o] = ak;
            PvT[b * 8192 + o * NT + (r0 + r)] = bf16rne(av);
        }
    } else if (blk < 140) {
        // W1P frags: fi = (ks*16+t)*64+l ; 3072 uint4
        int fi = (blk - 128) * 256 + tid;
        int l = fi & 63, rest = fi >> 6;
        int t = rest & 15, ks = rest >> 4;
        int n = t * 16 + (l & 15);
        int kb = ks * 32 + (l >> 4) * 8;
        unsigned short v[8];
        #pragma unroll
        for (int j = 0; j < 8; ++j) {
            int k = kb + j;
            v[j] = (k < XD) ? bf16rne(W1[n * XD + k]) : (unsigned short)0;
        }
        uint4 u;
        u.x = (unsigned)v[0] | ((unsigned)v[1] << 16);
        u.y = (unsigned)v[2] | ((unsigned)v[3] << 16);
        u.z = (unsigned)v[4] | ((unsigned)v[5] << 16);
        u.w = (unsigned)v[6] | ((unsigned)v[7] << 16);
        ((uint4*)(wsb + W1P_OFF))[fi] = u;
    } else {
        // W2P frags: 8192 uint4 over 32 blocks
        int fi = (blk - 140) * 256 + tid;
        int l = fi & 63, rest = fi >> 6;
        int t = rest & 15, ks = rest >> 4;
        int n = t * 16 + (l & 15);
        int kb = ks * 32 + (l >> 4) * 8;
        unsigned short v[8];
        #pragma unroll
        for (int j = 0; j < 8; ++j) v[j] = bf16rne(W2[n * NH1 + kb + j]);
        uint4 u;
        u.x = (unsigned)v[0] | ((unsigned)v[1] << 16);
        u.y = (unsigned)v[2] | ((unsigned)v[3] << 16);
        u.z = (unsigned)v[4] | ((unsigned)v[5] << 16);
        u.w = (unsigned)v[6] | ((unsigned)v[7] << 16);
        ((uint4*)(wsb + W2P_OFF))[fi] = u;
    }
}

// ---------------- K1: fused attention + MLP + heads ----------------
__global__ __launch_bounds__(512, 1) void actor_kernel(
    const float* __restrict__ state, const float* __restrict__ eps,
    const float* __restrict__ bkg, const float* __restrict__ bvg,
    const float* __restrict__ b1g, const float* __restrict__ b2g,
    const float* __restrict__ Wmu, const float* __restrict__ bmu,
    const float* __restrict__ Wls, const float* __restrict__ bls,
    const char* __restrict__ wsb, float* __restrict__ out)
{
    __shared__ __align__(16) char smraw[61440];
    float* smPk = (float*)smraw;                                   // [128][68] f32
    unsigned short* smPv = (unsigned short*)(smraw + 34816);       // [64][136] bf16
    _Float16* smP = (_Float16*)(smraw + 34816 + 17408);            // [64][72] f16
    unsigned short* Xb  = (unsigned short*)smraw;                  // alias [16][104]
    unsigned short* H1l = (unsigned short*)(smraw + 3328);         // [16][264]
    unsigned short* H2l = (unsigned short*)(smraw + 11776);        // [16][264]

    const int tid = threadIdx.x, w = tid >> 6, lane = tid & 63;
    const int bid = blockIdx.x;
    const int b = (bid & 7) * 4 + ((bid >> 3) & 3);   // XCD-affine: same b -> same XCD
    const int tile = bid >> 5;
    const int rA = 2 * w, rB = rA + 1;                // local rows 0..15
    const int iA = tile * 16 + rA, iB = iA + 1;       // global agent rows
    const int h = lane >> 4, s = lane & 15, h16 = h << 4;

    const float* Qg  = (const float*)(wsb + QG_OFF);
    const float* PkF = (const float*)(wsb + PKF_OFF);
    const unsigned short* PvT = (const unsigned short*)(wsb + PVT_OFF);

    // ---- global prefetches (overlap with LDS staging) ----
    float qA[16], qB[16], bkr[16];
    {
        const float4* qa = (const float4*)(Qg + ((size_t)b * NT + iA) * 64 + h16);
        const float4* qb = (const float4*)(Qg + ((size_t)b * NT + iB) * 64 + h16);
        const float4* bk4 = (const float4*)(bkg + h16);
        #pragma unroll
        for (int q4 = 0; q4 < 4; ++q4) {
            float4 a = qa[q4], c = qb[q4], k4 = bk4[q4];
            qA[q4*4+0]=a.x; qA[q4*4+1]=a.y; qA[q4*4+2]=a.z; qA[q4*4+3]=a.w;
            qB[q4*4+0]=c.x; qB[q4*4+1]=c.y; qB[q4*4+2]=c.z; qB[q4*4+3]=c.w;
            bkr[q4*4+0]=k4.x; bkr[q4*4+1]=k4.y; bkr[q4*4+2]=k4.z; bkr[q4*4+3]=k4.w;
        }
    }
    const float bvo = bvg[lane];
    float stt = 0.f;   // state tail for X cols 64..79 (lanes 0..31)
    if (lane < 32)
        stt = state[((size_t)b * NT + tile * 16 + 2 * w + (lane >> 4)) * KD + (lane & 15)];

    // ---- stage Pk (f32) and Pv (bf16) into LDS ----
    {
        const uint4* srcK = (const uint4*)(PkF + (size_t)b * NT * 64);
        #pragma unroll
        for (int it = 0; it < 4; ++it) {
            int idx = tid + it * 512;          // 2048 uint4
            int r = idx >> 4, c = idx & 15;
            *(uint4*)(smPk + r * 68 + c * 4) = srcK[idx];
        }
        const uint4* srcV = (const uint4*)(PvT + (size_t)b * 8192);
        #pragma unroll
        for (int it = 0; it < 2; ++it) {
            int idx = tid + it * 512;          // 1024 uint4
            int o = idx >> 4, c = idx & 15;
            *(uint4*)(smPv + o * 136 + c * 8) = srcV[idx];
        }
    }
    __syncthreads();

    // ---- per-row constants:  relu(x+c) = c + max(x,-c),  sum_j p_j = 1 ----
    float mbeffA[16], mbeffB[16];
    float dotA = 0.f, dotB = 0.f;
    {
        const float4* pa = (const float4*)(smPk + iA * 68 + h16);
        const float4* pb = (const float4*)(smPk + iB * 68 + h16);
        #pragma unroll
        for (int q4 = 0; q4 < 4; ++q4) {
            float4 va = pa[q4], vb = pb[q4];
            float fa[4] = {va.x, va.y, va.z, va.w};
            float fb[4] = {vb.x, vb.y, vb.z, vb.w};
            #pragma unroll
            for (int kk = 0; kk < 4; ++kk) {
                int k = q4 * 4 + kk;
                mbeffA[k] = fa[kk] - bkr[k];        // = Pk_i - bk  (the -c)
                mbeffB[k] = fb[kk] - bkr[k];
                dotA = fmaf(qA[k], -mbeffA[k], dotA);
                dotB = fmaf(qB[k], -mbeffB[k], dotB);
            }
        }
    }
    const float mbvA = bf2f(smPv[lane * 136 + iA]) - bvo;
    const float mbvB = bf2f(smPv[lane * 136 + iB]) - bvo;

    // ---- scores: lane (h,s) covers j = s + 16*jj ----
    float scA[8], scB[8];
    #pragma unroll
    for (int jj = 0; jj < 8; ++jj) {
        const float4* pk = (const float4*)(smPk + (s + (jj << 4)) * 68 + h16);
        float aA = dotA, aB = dotB;
        #pragma unroll
        for (int q4 = 0; q4 < 4; ++q4) {
            float4 v = pk[q4];
            float f[4] = {v.x, v.y, v.z, v.w};
            #pragma unroll
            for (int kk = 0; kk < 4; ++kk) {
                int k = q4 * 4 + kk;
                aA = fmaf(qA[k], fmaxf(f[kk], mbeffA[k]), aA);
                aB = fmaf(qB[k], fmaxf(f[kk], mbeffB[k]), aB);
            }
        }
        scA[jj] = aA; scB[jj] = aB;
    }

    // ---- softmax over 128 j within each 16-lane head group ----
    float mA = scA[0], mB = scB[0];
    #pragma unroll
    for (int jj = 1; jj < 8; ++jj) { mA = fmaxf(mA, scA[jj]); mB = fmaxf(mB, scB[jj]); }
    #pragma unroll
    for (int off = 1; off < 16; off <<= 1) {
        mA = fmaxf(mA, __shfl_xor(mA, off));
        mB = fmaxf(mB, __shfl_xor(mB, off));
    }
    float lA = 0.f, lB = 0.f;
    #pragma unroll
    for (int jj = 0; jj < 8; ++jj) {
        scA[jj] = __expf(scA[jj] - mA); lA += scA[jj];
        scB[jj] = __expf(scB[jj] - mB); lB += scB[jj];
    }
    #pragma unroll
    for (int off = 1; off < 16; off <<= 1) {
        lA += __shfl_xor(lA, off);
        lB += __shfl_xor(lB, off);
    }
    const float rlA = 1.0f / lA, rlB = 1.0f / lB;
    {
        _Float16* pwA = smP + (8 * w + h) * 72;
        _Float16* pwB = smP + (8 * w + 4 + h) * 72;
        #pragma unroll
        for (int jj = 0; jj < 8; ++jj) {
            pwA[(jj << 4) + s] = (_Float16)scA[jj];   // unnormalized p~ <= 1
            pwB[(jj << 4) + s] = (_Float16)scB[jj];
        }
    }
    __asm__ volatile("s_waitcnt lgkmcnt(0)" ::: "memory");   // same-wave LDS visibility

    // ---- PV: lane o = lane; x = -mbv + rl * sum_j p~_j * max(v_j, mbv) ----
    float accA = 0.f, accB = 0.f;
    {
        const unsigned short* pvo = smPv + lane * 136;
        const _Float16* pwA = smP + (8 * w + h) * 72;
        const _Float16* pwB = smP + (8 * w + 4 + h) * 72;
        #pragma unroll
        for (int u = 0; u < 16; ++u) {
            uint4 vv = *(const uint4*)(pvo + (u << 3));
            U4F16 pa, pb;
            pa.u = *(const uint4*)(pwA + (u << 3));
            pb.u = *(const uint4*)(pwB + (u << 3));
            float fv[8];
            unpack8(vv, fv);
            #pragma unroll
            for (int j = 0; j < 8; ++j) {
                float va = fmaxf(fv[j], mbvA);
                float vb = fmaxf(fv[j], mbvB);
                accA = fmaf((float)pa.h[j], va, accA);
                accB = fmaf((float)pb.h[j], vb, accB);
            }
        }
    }
    const float xA = fmaf(rlA, accA, -mbvA);
    const float xB = fmaf(rlB, accB, -mbvB);

    // prefetch MLP B-fragments (global, consumed after barriers)
    const uint4* W1P = (const uint4*)(wsb + W1P_OFF);
    const uint4* W2P = (const uint4*)(wsb + W2P_OFF);
    const int t0 = 2 * w;
    uint4 w1f[3][2], w2f[8][2];
    #pragma unroll
    for (int ks = 0; ks < 3; ++ks) {
        w1f[ks][0] = W1P[((ks << 4) + t0) * 64 + lane];
        w1f[ks][1] = W1P[((ks << 4) + t0 + 1) * 64 + lane];
    }
    #pragma unroll
    for (int ks = 0; ks < 8; ++ks) {
        w2f[ks][0] = W2P[((ks << 4) + t0) * 64 + lane];
        w2f[ks][1] = W2P[((ks << 4) + t0 + 1) * 64 + lane];
    }

    __syncthreads();   // all Pk/Pv reads done; safe to alias

    // ---- write X (bf16, 96-col padded) into alias region ----
    Xb[rA * 104 + lane] = bf16rne(xA);
    Xb[rB * 104 + lane] = bf16rne(xB);
    if (lane < 32)
        Xb[(2 * w + (lane >> 4)) * 104 + 64 + (lane & 15)] = bf16rne(stt);
    else
        Xb[(2 * w + ((lane >> 4) & 1)) * 104 + 80 + (lane & 15)] = 0;
    __syncthreads();

    // ---- layer 1 (MFMA): wave w covers neurons t0*16 .. t0*16+31 ----
    const int lr = s, g = h;   // A-frag: row = lane&15, k-block = lane>>4
    const f32x4 z4 = {0.f, 0.f, 0.f, 0.f};
    {
        f32x4 a0 = z4, a1 = z4;
        #pragma unroll
        for (int ks = 0; ks < 3; ++ks) {
            U4B8 av; av.u = *(const uint4*)(Xb + lr * 104 + (ks << 5) + (g << 3));
            U4B8 b0; b0.u = w1f[ks][0];
            U4B8 b1v; b1v.u = w1f[ks][1];
            a0 = __builtin_amdgcn_mfma_f32_16x16x32_bf16(av.h, b0.h, a0, 0, 0, 0);
            a1 = __builtin_amdgcn_mfma_f32_16x16x32_bf16(av.h, b1v.h, a1, 0, 0, 0);
        }
        const int n0 = t0 * 16 + lr, n1 = n0 + 16;
        const float bn0 = b1g[n0], bn1 = b1g[n1];
        #pragma unroll
        for (int qq = 0; qq < 4; ++qq) {
            H1l[(4 * g + qq) * 264 + n0] = bf16rne(fmaxf(a0[qq] + bn0, 0.f));
            H1l[(4 * g + qq) * 264 + n1] = bf16rne(fmaxf(a1[qq] + bn1, 0.f));
        }
    }
    __syncthreads();

    // ---- layer 2 (MFMA) ----
    {
        f32x4 a0 = z4, a1 = z4;
        #pragma unroll
        for (int ks = 0; ks < 8; ++ks) {
            U4B8 av; av.u = *(const uint4*)(H1l + lr * 264 + (ks << 5) + (g << 3));
            U4B8 b0; b0.u = w2f[ks][0];
            U4B8 b1v; b1v.u = w2f[ks][1];
            a0 = __builtin_amdgcn_mfma_f32_16x16x32_bf16(av.h, b0.h, a0, 0, 0, 0);
            a1 = __builtin_amdgcn_mfma_f32_16x16x32_bf16(av.h, b1v.h, a1, 0, 0, 0);
        }
        const int n0 = t0 * 16 + lr, n1 = n0 + 16;
        const float bn0 = b2g[n0], bn1 = b2g[n1];
        #pragma unroll
        for (int qq = 0; qq < 4; ++qq) {
            H2l[(4 * g + qq) * 264 + n0] = bf16rne(fmaxf(a0[qq] + bn0, 0.f));
            H2l[(4 * g + qq) * 264 + n1] = bf16rne(fmaxf(a1[qq] + bn1, 0.f));
        }
    }
    __syncthreads();

    // ---- heads + finalize (first 256 threads: row m, k-slice cc) ----
    if (tid < 256) {
        const int m = tid >> 4, cc = tid & 15;
        float hbuf[16];
        uint4 ha = *(const uint4*)(H2l + m * 264 + cc * 16);
        uint4 hb = *(const uint4*)(H2l + m * 264 + cc * 16 + 8);
        unpack8(ha, hbuf); unpack8(hb, hbuf + 8);
        float d0 = 0.f, d1 = 0.f, d2 = 0.f, d3 = 0.f;
        #pragma unroll
        for (int kk = 0; kk < 16; ++kk) {
            int k = cc * 16 + kk;
            float hv = hbuf[kk];
            d0 = fmaf(hv, Wmu[k], d0);
            d1 = fmaf(hv, Wmu[256 + k], d1);
            d2 = fmaf(hv, Wls[k], d2);
            d3 = fmaf(hv, Wls[256 + k], d3);
        }
        #pragma unroll
        for (int off = 1; off < 16; off <<= 1) {
            d0 += __shfl_xor(d0, off);
            d1 += __shfl_xor(d1, off);
            d2 += __shfl_xor(d2, off);
            d3 += __shfl_xor(d3, off);
        }
        if (cc == 0) {
            const int row = b * NT + tile * 16 + m;
            float mu0 = tanhf(d0 + bmu[0]);
            float mu1 = tanhf(d1 + bmu[1]);
            float t2  = tanhf(d2 + bls[0]);
            float t3  = tanhf(d3 + bls[1]);
            float ls0 = -20.f + 11.f * (t2 + 1.f);
            float ls1 = -20.f + 11.f * (t3 + 1.f);
            float e0 = eps[row * 2], e1 = eps[row * 2 + 1];
            float z0 = mu0 + __expf(ls0) * e0;
            float z1 = mu1 + __expf(ls1) * e1;
            float a0 = tanhf(z0), a1 = tanhf(z1);
            out[row * 2]     = a0;
            out[row * 2 + 1] = a1;
            float lp = -0.5f * e0 * e0 - ls0 - 0.91893853320467274f - __logf(1.f - a0 * a0 + 1e-7f)
                     + -0.5f * e1 * e1 - ls1 - 0.91893853320467274f - __logf(1.f - a1 * a1 + 1e-7f);
            out[NB * NT * 2 + row] = lp;
        }
    }
}

extern "C" void kernel_launch(void* const* d_in, const int* in_sizes, int n_in,
                              void* d_out, int out_size, void* d_ws, size_t ws_size,
                              hipStream_t stream) {
    const float* state = (const float*)d_in[0];
    const float* eps   = (const float*)d_in[1];
    const float* Wq    = (const float*)d_in[2];
    const float* bq    = (const float*)d_in[3];
    const float* Wk    = (const float*)d_in[4];
    const float* bk    = (const float*)d_in[5];
    const float* Wv    = (const float*)d_in[6];
    const float* bv    = (const float*)d_in[7];
    const float* W1    = (const float*)d_in[8];
    const float* b1    = (const float*)d_in[9];
    const float* W2    = (const float*)d_in[10];
    const float* b2    = (const float*)d_in[11];
    const float* Wmu   = (const float*)d_in[12];
    const float* bmu   = (const float*)d_in[13];
    const float* Wls   = (const float*)d_in[14];
    const float* bls   = (const float*)d_in[15];
    float* out = (float*)d_out;
    char* wsb  = (char*)d_ws;

    prep_kernel<<<172, 256, 0, stream>>>(state, Wq, bq, Wk, Wv, W1, W2, wsb);
    actor_kernel<<<256, 512, 0, stream>>>(state, eps, bk, bv, b1, b2,
                                          Wmu, bmu, Wls, bls, wsb, out);
}